// Round 8
// baseline (2098.910 us; speedup 1.0000x reference)
//
#include <hip/hip_runtime.h>
#include <hip/hip_fp16.h>
#include <math.h>

#define TWO_PI_F 6.2831853071795864769f

constexpr int T     = 256;
constexpr int BATCH = 32;
constexpr int NIN   = 28;
constexpr int NH    = 1024;
constexpr int NOUT  = 10;

// 128 blocks: xslot = bid&7 (presumed XCD under round-robin); xslot<4 active.
constexpr int NBLK = 128;
constexpr int NTHR = 512;    // 8 waves: wave w -> (row-tile = w&3, khalf = w>>2)

typedef unsigned int   uint;
typedef unsigned short ushort;
typedef _Float16 half8 __attribute__((ext_vector_type(8)));
typedef float    f32x4 __attribute__((ext_vector_type(4)));

// ---- ws byte offsets ----
constexpr size_t OFF_W16 = 0;                                    // ushort [1024][1024] fp16 W = 2 MB
constexpr size_t OFF_INP = 2ull * 1024 * 1024;                   // float [T][BATCH][NH] = 32 MB
constexpr size_t OFF_SCT = OFF_INP + (size_t)T * NH * BATCH * 4; // ushort [2][4][16][1024] = 256 KB
constexpr size_t OFF_STF = OFF_SCT + 2ull * 4 * 16 * 1024 * 2;   // float [BATCH][NH] = 128 KB
constexpr size_t OFF_FLG = OFF_STF + (size_t)BATCH * NH * 4;
// flags layout (uints): [0:2048) slow step flags | [2048:4096) fast step flags |
// [4096:6144) init flags | [6144:6208) xcc table | [6208:6212) votes

__device__ __forceinline__ void st32(uint* p, uint v) {
  __hip_atomic_store(p, v, __ATOMIC_RELAXED, __HIP_MEMORY_SCOPE_AGENT);
}

__device__ __forceinline__ uint get_xcc() {
  uint x;
  asm volatile("s_getreg_b32 %0, hwreg(HW_REG_XCC_ID)" : "=s"(x));
  return x & 0xffu;
}

// sc0 load: bypass L1, read the XCD's shared L2.
__device__ __forceinline__ uint ld32_sc0(const uint* p) {
  uint v;
  asm volatile("global_load_dword %0, %1, off sc0\n\ts_waitcnt vmcnt(0)"
               : "=v"(v) : "v"(p) : "memory");
  return v;
}

// Batched B-fragment load, device scope (sc1 -> LLC). R6-proven.
__device__ __forceinline__ void ldB_sc1(const ushort* base, uint4 bf[16]) {
  asm volatile(
    "global_load_dwordx4 %0, %16, off sc1\n\t"
    "global_load_dwordx4 %1, %16, off offset:64 sc1\n\t"
    "global_load_dwordx4 %2, %16, off offset:128 sc1\n\t"
    "global_load_dwordx4 %3, %16, off offset:192 sc1\n\t"
    "global_load_dwordx4 %4, %16, off offset:256 sc1\n\t"
    "global_load_dwordx4 %5, %16, off offset:320 sc1\n\t"
    "global_load_dwordx4 %6, %16, off offset:384 sc1\n\t"
    "global_load_dwordx4 %7, %16, off offset:448 sc1\n\t"
    "global_load_dwordx4 %8, %16, off offset:512 sc1\n\t"
    "global_load_dwordx4 %9, %16, off offset:576 sc1\n\t"
    "global_load_dwordx4 %10, %16, off offset:640 sc1\n\t"
    "global_load_dwordx4 %11, %16, off offset:704 sc1\n\t"
    "global_load_dwordx4 %12, %16, off offset:768 sc1\n\t"
    "global_load_dwordx4 %13, %16, off offset:832 sc1\n\t"
    "global_load_dwordx4 %14, %16, off offset:896 sc1\n\t"
    "global_load_dwordx4 %15, %16, off offset:960 sc1\n\t"
    "s_waitcnt vmcnt(0)"
    : "=&v"(bf[0]), "=&v"(bf[1]), "=&v"(bf[2]), "=&v"(bf[3]),
      "=&v"(bf[4]), "=&v"(bf[5]), "=&v"(bf[6]), "=&v"(bf[7]),
      "=&v"(bf[8]), "=&v"(bf[9]), "=&v"(bf[10]), "=&v"(bf[11]),
      "=&v"(bf[12]), "=&v"(bf[13]), "=&v"(bf[14]), "=&v"(bf[15])
    : "v"(base)
    : "memory");
}

// Same with sc0: L1-bypass, shared-L2 read. Correct for same-XCD chains where
// producers use PLAIN stores (which update the shared L2 in place).
__device__ __forceinline__ void ldB_sc0(const ushort* base, uint4 bf[16]) {
  asm volatile(
    "global_load_dwordx4 %0, %16, off sc0\n\t"
    "global_load_dwordx4 %1, %16, off offset:64 sc0\n\t"
    "global_load_dwordx4 %2, %16, off offset:128 sc0\n\t"
    "global_load_dwordx4 %3, %16, off offset:192 sc0\n\t"
    "global_load_dwordx4 %4, %16, off offset:256 sc0\n\t"
    "global_load_dwordx4 %5, %16, off offset:320 sc0\n\t"
    "global_load_dwordx4 %6, %16, off offset:384 sc0\n\t"
    "global_load_dwordx4 %7, %16, off offset:448 sc0\n\t"
    "global_load_dwordx4 %8, %16, off offset:512 sc0\n\t"
    "global_load_dwordx4 %9, %16, off offset:576 sc0\n\t"
    "global_load_dwordx4 %10, %16, off offset:640 sc0\n\t"
    "global_load_dwordx4 %11, %16, off offset:704 sc0\n\t"
    "global_load_dwordx4 %12, %16, off offset:768 sc0\n\t"
    "global_load_dwordx4 %13, %16, off offset:832 sc0\n\t"
    "global_load_dwordx4 %14, %16, off offset:896 sc0\n\t"
    "global_load_dwordx4 %15, %16, off offset:960 sc0\n\t"
    "s_waitcnt vmcnt(0)"
    : "=&v"(bf[0]), "=&v"(bf[1]), "=&v"(bf[2]), "=&v"(bf[3]),
      "=&v"(bf[4]), "=&v"(bf[5]), "=&v"(bf[6]), "=&v"(bf[7]),
      "=&v"(bf[8]), "=&v"(bf[9]), "=&v"(bf[10]), "=&v"(bf[11]),
      "=&v"(bf[12]), "=&v"(bf[13]), "=&v"(bf[14]), "=&v"(bf[15])
    : "v"(base)
    : "memory");
}

// ---- publish: ALWAYS the proven agent-release (LLC backstop). FAST chains
// additionally store a fast flag AFTER it (wg-release, lands in shared L2).
// Ordering: __syncthreads drains every wave's vmcnt (data ACKed >= L2);
// agent-release wbl2+waitcnt complete before the fast store issues, so
// fast-flag-seen => data visible (L2 in place AND written back to LLC).
template<bool FAST>
__device__ __forceinline__ void gbar_pub(unsigned* slowf, unsigned* fastf,
                                         unsigned step, int tid, int rg, int bg) {
  __syncthreads();
  if (tid == 0) {
    __hip_atomic_store(&slowf[(bg * 16 + rg) * 32], step, __ATOMIC_RELEASE,
                       __HIP_MEMORY_SCOPE_AGENT);
    if (FAST)
      __hip_atomic_store(&fastf[(bg * 16 + rg) * 32], step, __ATOMIC_RELEASE,
                         __HIP_MEMORY_SCOPE_WORKGROUP);
  }
}

// ---- wait: FAST polls the L2 fast flag with a tiny budget, then falls back
// to the proven slow flag. Never free-runs, never deadlocks: worst case is
// the slow protocol plus ~2-3us of budget per step.
template<bool FAST>
__device__ __forceinline__ void gbar_wait(unsigned* slowf, unsigned* fastf,
                                          unsigned step, int tid, int bg) {
  if (tid < 16) {
    bool got = false;
    if (FAST) {
      const uint* fp = (const uint*)&fastf[(bg * 16 + tid) * 32];
      for (int it = 0; it < 24; ++it) {
        if (ld32_sc0(fp) >= step) { got = true; break; }
        __builtin_amdgcn_s_sleep(1);
      }
    }
    if (!got)
      while (__hip_atomic_load(&slowf[(bg * 16 + tid) * 32], __ATOMIC_RELAXED,
                               __HIP_MEMORY_SCOPE_AGENT) < step)
        __builtin_amdgcn_s_sleep(1);
  }
  __syncthreads();
}

// One-time 64-block init barrier (LLC protocol, placement-agnostic).
// ACQUIRE spin synchronizes-with each block's release flag store.
__device__ __forceinline__ void gbar_init(unsigned* f, int tid, int aid, unsigned tgt) {
  __syncthreads();
  if (tid == 0)
    __hip_atomic_store(&f[aid * 32], tgt, __ATOMIC_RELEASE, __HIP_MEMORY_SCOPE_AGENT);
  if (tid < 64) {
    while (__hip_atomic_load(&f[tid * 32], __ATOMIC_ACQUIRE,
                             __HIP_MEMORY_SCOPE_AGENT) < tgt)
      __builtin_amdgcn_s_sleep(1);
  }
  __syncthreads();
}

// ---- prep: W -> fp16 ----
__global__ __launch_bounds__(256) void prep_w16(const float* __restrict__ Wh,
                                                ushort* __restrict__ w16) {
  const int m = blockIdx.x * 256 + threadIdx.x;
  w16[m] = __builtin_bit_cast(ushort, (_Float16)Wh[m]);
}

// ---- prep: inp[t][b][i] = Wi_w[i,:]·x[t,b,:] + Wi_b[i] + omega[i] ----
__global__ __launch_bounds__(256) void prep_inp(const float* __restrict__ x,
                                                const float* __restrict__ Wi_w,
                                                const float* __restrict__ Wi_b,
                                                const float* __restrict__ omega,
                                                float* __restrict__ inp) {
  const int t = blockIdx.x;
  const int b = blockIdx.y;
  const float* xr = x + ((size_t)t * BATCH + b) * NIN;
#pragma unroll
  for (int u = 0; u < 4; ++u) {
    const int i = u * 256 + threadIdx.x;
    const float* wr = Wi_w + (size_t)i * NIN;
    float acc = Wi_b[i] + omega[i];
#pragma unroll
    for (int k = 0; k < NIN; ++k) acc += xr[k] * wr[k];
    inp[((size_t)t * BATCH + b) * NH + i] = acc;
  }
}

template<bool FAST>
__device__ __forceinline__ float scan_loop(
    const float* __restrict__ inp, const half8 (&af)[16],
    ushort* __restrict__ scT, unsigned* __restrict__ slowf,
    unsigned* __restrict__ fastf, float* pd,
    int tid, int rg, int bg, int m, int quad, int kh, int rt,
    int bl, int ilc, int i, int b)
{
  // ---- init parity-0 state: FAST = plain (updates shared L2 in place),
  // SLOW = proven st32. Both covered by the agent-release in gbar_pub.
  if ((ilc & 1) == 0) {
    uint* a0 = (uint*)(scT + ((size_t)(0 * 4 + bg) * 16 + bl) * 1024 + i);
    if (FAST) *(volatile uint*)a0 = 0x00000000u; else st32(a0, 0x00000000u);     // sin = 0,0
  } else {
    uint* a1 = (uint*)(scT + ((size_t)(0 * 4 + bg) * 16 + bl + 8) * 1024 + (i - 1));
    if (FAST) *(volatile uint*)a1 = 0x3C003C00u; else st32(a1, 0x3C003C00u);     // cos = 1,1
  }

  float th = 0.f, s_own = 0.f, c_own = 1.f;

  unsigned step = 1;
  gbar_pub<FAST>(slowf, fastf, step, tid, rg, bg);
  float inpv = inp[(size_t)b * NH + i];   // t=0 prefetch drains under the wait
  gbar_wait<FAST>(slowf, fastf, step, tid, bg);
  ++step;

  for (int t = 0; t < T; ++t) {
    const int p = t & 1;

    // ---- B-fragments: my batch-group's 16 state rows (32 KB/block) ----
    uint4 bf[16];
    const ushort* bbase = scT + ((size_t)(p * 4 + bg) * 16 + m) * 1024 + kh * 512 + quad * 8;
    if (FAST) ldB_sc0(bbase, bf); else ldB_sc1(bbase, bf);

    // ---- MFMA: two independent 8-chains, then add ----
    f32x4 D0 = {0.f, 0.f, 0.f, 0.f}, D1 = {0.f, 0.f, 0.f, 0.f};
#pragma unroll
    for (int ks = 0; ks < 8; ++ks)
      D0 = __builtin_amdgcn_mfma_f32_16x16x32_f16(af[ks], __builtin_bit_cast(half8, bf[ks]), D0, 0, 0, 0);
#pragma unroll
    for (int ks = 8; ks < 16; ++ks)
      D1 = __builtin_amdgcn_mfma_f32_16x16x32_f16(af[ks], __builtin_bit_cast(half8, bf[ks]), D1, 0, 0, 0);
    const f32x4 D = D0 + D1;

    // lane holds D rows quad*4..+3 (M) of column m (N) -> pd[kh][rt][m][quad*4..]
    *(f32x4*)&pd[(((kh * 4 + rt) * 16) + m) * 20 + quad * 4] = D;
    __syncthreads();

    // ---- theta update for (i, b) ----
    const int rti = ilc >> 4, r16 = ilc & 15;
    const float S = pd[((0 + rti) * 16 + bl) * 20 + r16] + pd[((4 + rti) * 16 + bl) * 20 + r16];
    const float C = pd[((0 + rti) * 16 + bl + 8) * 20 + r16] + pd[((4 + rti) * 16 + bl + 8) * 20 + r16];
    const float coup = s_own * C - c_own * S;   // sin*ΣWcos - cos*ΣWsin
    th = fmodf(coup + inpv + th, TWO_PI_F);
    if (th < 0.f) th += TWO_PI_F;
    float s, c;
    sincosf(th, &s, &c);
    s_own = s; c_own = c;

    if (t == T - 1) break;

    // ---- publish fp16 state, paired lanes -> one uint store each ----
    const uint hs = __builtin_bit_cast(ushort, (_Float16)s);
    const uint hc = __builtin_bit_cast(ushort, (_Float16)c);
    const uint phs = (uint)__shfl_xor((int)hs, 1, 64);
    const uint phc = (uint)__shfl_xor((int)hc, 1, 64);
    const size_t dbase = (size_t)((p ^ 1) * 4 + bg) * 16;
    uint* addr; uint val;
    if ((ilc & 1) == 0) { addr = (uint*)(scT + (dbase + bl) * 1024 + i);           val = hs | (phs << 16); }
    else                { addr = (uint*)(scT + (dbase + bl + 8) * 1024 + (i - 1)); val = phc | (hc << 16); }
    if (FAST) *(volatile uint*)addr = val; else st32(addr, val);

    gbar_pub<FAST>(slowf, fastf, step, tid, rg, bg);
    inpv = inp[((size_t)(t + 1) * BATCH + b) * NH + i];   // drains under the wait
    gbar_wait<FAST>(slowf, fastf, step, tid, bg);
    ++step;
  }
  return th;
}

__global__ __launch_bounds__(NTHR, 2) void kuramoto_scan(
    const float*  __restrict__ inp,   // [T][BATCH][NH]
    const ushort* __restrict__ w16,   // [1024][1024] fp16
    ushort*       __restrict__ scT,   // [2][4 bg][16 n][1024 i]; n: 0-7 sin, 8-15 cos
    float*        __restrict__ stF,   // [BATCH][NH]
    unsigned*     __restrict__ flags)
{
  __shared__ float pd[2 * 4 * 16 * 20];   // 10 KB
  __shared__ unsigned sverdict;

  const int tid   = threadIdx.x;
  const int bid   = blockIdx.x;
  const int xslot = bid & 7;        // presumed XCD under round-robin
  if (xslot >= 4) return;           // 64 idle blocks exit immediately
  const int bg    = xslot;          // chain id: all 16 blocks share a residue
  const int rg    = bid >> 3;       // row-group: rows rg*64 .. +63
  const int aid   = bg * 16 + rg;   // 0..63 over active blocks

  unsigned* slowf  = flags;
  unsigned* fastf  = flags + 2048;
  unsigned* iniflg = flags + 4096;
  unsigned* xcctab = flags + 6144;
  unsigned* votes  = flags + 6208;

  const int lane = tid & 63;
  const int w    = tid >> 6;
  const int rt   = w & 3;          // row-tile within block (16 rows)
  const int kh   = w >> 2;         // K-half
  const int m    = lane & 15;      // A: M index / B,D: N index
  const int quad = lane >> 4;

  // ---- A-fragments (W rows) once into registers: 16 frags x 4 VGPR ----
  half8 af[16];
  {
    const ushort* wbase = w16 + (size_t)(rg * 64 + rt * 16 + m) * NH + kh * 512 + quad * 8;
#pragma unroll
    for (int ks = 0; ks < 16; ++ks)
      af[ks] = __builtin_bit_cast(half8, *(const uint4*)(wbase + ks * 32));
  }

  const int bl  = tid >> 6;        // 0..7
  const int ilc = tid & 63;        // 0..63
  const int i   = rg * 64 + ilc;   // my hidden unit
  const int b   = bg * 8 + bl;     // my batch

  // ---- placement verdict (deadlock-proof, r7 machinery) ----
  if (tid == 0) st32(&xcctab[aid], get_xcc() | 0x100u);
  gbar_init(iniflg, tid, aid, 1u);

  if (tid == 0) {
    const uint x0 = __hip_atomic_load(&xcctab[bg * 16 + 0], __ATOMIC_RELAXED,
                                      __HIP_MEMORY_SCOPE_AGENT);
    bool myfast = ((x0 >> 8) == 1u);   // marker REQUIRED (stale 0s -> slow)
#pragma unroll
    for (int j = 1; j < 16; ++j)
      myfast &= (__hip_atomic_load(&xcctab[bg * 16 + j], __ATOMIC_RELAXED,
                                   __HIP_MEMORY_SCOPE_AGENT) == x0);
    atomicAdd(&votes[bg], myfast ? 0x10001u : 0x1u);
  }
  gbar_init(iniflg, tid, aid, 2u);
  if (tid == 0) sverdict = atomicAdd(&votes[bg], 0u);   // coherent readback
  __syncthreads();
  const bool fast = (sverdict == 0x00100010u);          // 16 voters, 16 fast

  const float th = fast
    ? scan_loop<true >(inp, af, scT, slowf, fastf, pd, tid, rg, bg, m, quad, kh, rt, bl, ilc, i, b)
    : scan_loop<false>(inp, af, scT, slowf, fastf, pd, tid, rg, bg, m, quad, kh, rt, bl, ilc, i, b);

  stF[(size_t)b * NH + i] = th;   // kernel-end writeback publishes to readout
}

// ---- readout ----
__global__ void readout(const float* __restrict__ stF,
                        const float* __restrict__ Wout,   // [10][1024]
                        const float* __restrict__ bout,   // [10]
                        float* __restrict__ out)          // [32][10]
{
  const int bb = blockIdx.x;
  const int lane = threadIdx.x;   // 64 threads
  float st[16];
#pragma unroll
  for (int u = 0; u < 16; ++u) st[u] = stF[(size_t)bb * NH + u * 64 + lane];
  for (int o = 0; o < NOUT; ++o) {
    float acc = 0.f;
#pragma unroll
    for (int u = 0; u < 16; ++u) acc += st[u] * Wout[o * NH + u * 64 + lane];
#pragma unroll
    for (int sh = 1; sh < 64; sh <<= 1) acc += __shfl_xor(acc, sh, 64);
    if (lane == 0) out[bb * NOUT + o] = acc + bout[o];
  }
}

extern "C" void kernel_launch(void* const* d_in, const int* in_sizes, int n_in,
                              void* d_out, int out_size, void* d_ws, size_t ws_size,
                              hipStream_t stream) {
  const float* x     = (const float*)d_in[0];
  const float* Wi_w  = (const float*)d_in[1];
  const float* Wi_b  = (const float*)d_in[2];
  const float* Wh    = (const float*)d_in[3];
  const float* omega = (const float*)d_in[4];
  const float* W_out = (const float*)d_in[5];
  const float* b_out = (const float*)d_in[6];

  char* ws = (char*)d_ws;
  ushort*   w16 = (ushort*)(ws + OFF_W16);
  float*    inp = (float*)(ws + OFF_INP);
  ushort*   scT = (ushort*)(ws + OFF_SCT);
  float*    stF = (float*)(ws + OFF_STF);
  unsigned* flg = (unsigned*)(ws + OFF_FLG);

  (void)hipMemsetAsync(ws + OFF_FLG, 0, 6212 * 4 + 64, stream);

  prep_w16<<<dim3(NH * NH / 256), dim3(256), 0, stream>>>(Wh, w16);
  prep_inp<<<dim3(T, BATCH), dim3(256), 0, stream>>>(x, Wi_w, Wi_b, omega, inp);

  void* args[] = { (void*)&inp, (void*)&w16, (void*)&scT, (void*)&stF, (void*)&flg };
  hipError_t err = hipLaunchCooperativeKernel((const void*)kuramoto_scan,
                                              dim3(NBLK), dim3(NTHR), args, 0, stream);
  if (err != hipSuccess) {
    // 128 blocks at <=2 blocks/CU are trivially co-resident; normal launch is safe.
    (void)hipGetLastError();
    kuramoto_scan<<<dim3(NBLK), dim3(NTHR), 0, stream>>>(inp, w16, scT, stF, flg);
  }

  readout<<<dim3(BATCH), dim3(64), 0, stream>>>(stF, W_out, b_out, (float*)d_out);
}

// Round 9
// 1659.050 us; speedup vs baseline: 1.2651x; 1.2651x over previous
//
#include <hip/hip_runtime.h>
#include <hip/hip_fp16.h>
#include <math.h>

#define TWO_PI_F 6.2831853071795864769f

constexpr int T     = 256;
constexpr int BATCH = 32;
constexpr int NIN   = 28;
constexpr int NH    = 1024;
constexpr int NOUT  = 10;

constexpr int NBLK = 64;     // 16 row-groups x 4 batch-groups
constexpr int NTHR = 512;    // 8 waves: wave w -> (row-tile = w&3, khalf = w>>2)

typedef unsigned int   uint;
typedef unsigned short ushort;
typedef _Float16 half8 __attribute__((ext_vector_type(8)));
typedef float    f32x4 __attribute__((ext_vector_type(4)));

// ---- ws byte offsets ----
constexpr size_t OFF_W16 = 0;                                    // ushort [1024][1024] fp16 W = 2 MB
constexpr size_t OFF_INP = 2ull * 1024 * 1024;                   // float [T][BATCH][NH] = 32 MB
constexpr size_t OFF_SCT = OFF_INP + (size_t)T * NH * BATCH * 4; // ushort [2][4][16][1024] = 256 KB
constexpr size_t OFF_STF = OFF_SCT + 2ull * 4 * 16 * 1024 * 2;   // float [BATCH][NH] = 128 KB
constexpr size_t OFF_FLG = OFF_STF + (size_t)BATCH * NH * 4;     // step flags, 8 KB

// keep a value live without cost: forces the compiler to emit the
// returning (sc0) atomic whose vmcnt ACK = executed-at-LLC.
__device__ __forceinline__ void sink(uint v) { asm volatile("" :: "v"(v)); }

// LLC-point publish of one state word: far-atomic exchange. The RMW executes
// AT the device coherence point (LLC) -- no dirty L2 line, no wbl2 needed
// later. vmcnt ACK (forced by the consumed return) = globally visible.
__device__ __forceinline__ void stx(uint* p, uint v) {
  sink(atomicExch(p, v));
}

// Batched device-scope (sc1) B-fragment load: 16 x dwordx4 at 64B stride from
// one base, ONE waitcnt (R6-proven; reads the LLC, immune to stale L2).
__device__ __forceinline__ void ldB(const ushort* base, uint4 bf[16]) {
  asm volatile(
    "global_load_dwordx4 %0, %16, off sc1\n\t"
    "global_load_dwordx4 %1, %16, off offset:64 sc1\n\t"
    "global_load_dwordx4 %2, %16, off offset:128 sc1\n\t"
    "global_load_dwordx4 %3, %16, off offset:192 sc1\n\t"
    "global_load_dwordx4 %4, %16, off offset:256 sc1\n\t"
    "global_load_dwordx4 %5, %16, off offset:320 sc1\n\t"
    "global_load_dwordx4 %6, %16, off offset:384 sc1\n\t"
    "global_load_dwordx4 %7, %16, off offset:448 sc1\n\t"
    "global_load_dwordx4 %8, %16, off offset:512 sc1\n\t"
    "global_load_dwordx4 %9, %16, off offset:576 sc1\n\t"
    "global_load_dwordx4 %10, %16, off offset:640 sc1\n\t"
    "global_load_dwordx4 %11, %16, off offset:704 sc1\n\t"
    "global_load_dwordx4 %12, %16, off offset:768 sc1\n\t"
    "global_load_dwordx4 %13, %16, off offset:832 sc1\n\t"
    "global_load_dwordx4 %14, %16, off offset:896 sc1\n\t"
    "global_load_dwordx4 %15, %16, off offset:960 sc1\n\t"
    "s_waitcnt vmcnt(0)"
    : "=&v"(bf[0]), "=&v"(bf[1]), "=&v"(bf[2]), "=&v"(bf[3]),
      "=&v"(bf[4]), "=&v"(bf[5]), "=&v"(bf[6]), "=&v"(bf[7]),
      "=&v"(bf[8]), "=&v"(bf[9]), "=&v"(bf[10]), "=&v"(bf[11]),
      "=&v"(bf[12]), "=&v"(bf[13]), "=&v"(bf[14]), "=&v"(bf[15])
    : "v"(base)
    : "memory");
}

// Per-chain barrier, ATOMIC-PUBLISH protocol (no agent-release, no wbl2):
//  - data words were published via stx (far atomics, LLC-executed).
//  - __syncthreads drains every wave's vmcnt before s_barrier (m97 asm) =>
//    ALL data atomics executed at the LLC before any thread passes.
//  - tid0 then publishes the flag with another far atomic.
//  - consumers spin with relaxed agent loads (harness-proven to observe
//    LLC updates), then read data with sc1 loads (LLC, proven fresh).
__device__ __forceinline__ void gbar_pub(unsigned* flags, unsigned step, int tid,
                                         int rg, int bg) {
  __syncthreads();
  if (tid == 0)
    sink(atomicExch(&flags[(bg * 16 + rg) * 32], step));
}

__device__ __forceinline__ void gbar_wait(unsigned* flags, unsigned step, int tid,
                                          int bg) {
  if (tid < 16)
    while (__hip_atomic_load(&flags[(bg * 16 + tid) * 32], __ATOMIC_RELAXED,
                             __HIP_MEMORY_SCOPE_AGENT) < step)
      __builtin_amdgcn_s_sleep(1);
  __syncthreads();
}

// ---- prep: W -> fp16 ----
__global__ __launch_bounds__(256) void prep_w16(const float* __restrict__ Wh,
                                                ushort* __restrict__ w16) {
  const int m = blockIdx.x * 256 + threadIdx.x;
  w16[m] = __builtin_bit_cast(ushort, (_Float16)Wh[m]);
}

// ---- prep: inp[t][b][i] = Wi_w[i,:]·x[t,b,:] + Wi_b[i] + omega[i] ----
__global__ __launch_bounds__(256) void prep_inp(const float* __restrict__ x,
                                                const float* __restrict__ Wi_w,
                                                const float* __restrict__ Wi_b,
                                                const float* __restrict__ omega,
                                                float* __restrict__ inp) {
  const int t = blockIdx.x;
  const int b = blockIdx.y;
  const float* xr = x + ((size_t)t * BATCH + b) * NIN;
#pragma unroll
  for (int u = 0; u < 4; ++u) {
    const int i = u * 256 + threadIdx.x;
    const float* wr = Wi_w + (size_t)i * NIN;
    float acc = Wi_b[i] + omega[i];
#pragma unroll
    for (int k = 0; k < NIN; ++k) acc += xr[k] * wr[k];
    inp[((size_t)t * BATCH + b) * NH + i] = acc;
  }
}

// ---- the scan: block = (row-group, batch-group); 4 independent bg-chains ----
__global__ __launch_bounds__(NTHR, 2) void kuramoto_scan(
    const float*  __restrict__ inp,   // [T][BATCH][NH]
    const ushort* __restrict__ w16,   // [1024][1024] fp16
    ushort*       __restrict__ scT,   // [2][4 bg][16 n][1024 i]; n: 0-7 sin, 8-15 cos
    float*        __restrict__ stF,   // [BATCH][NH]
    unsigned*     __restrict__ flags)
{
  // D-partials: pd[kh][rt][n][row16 (+4 pad)]
  __shared__ float pd[2 * 4 * 16 * 20];   // 10 KB

  const int tid  = threadIdx.x;
  const int bid  = blockIdx.x;
  const int rg   = bid >> 2;       // row-group: rows rg*64 .. +63
  const int bg   = bid & 3;        // batch-group: batches bg*8 .. +7
  const int lane = tid & 63;
  const int w    = tid >> 6;
  const int rt   = w & 3;          // row-tile within block (16 rows)
  const int kh   = w >> 2;         // K-half
  const int m    = lane & 15;      // A: M index / B,D: N index
  const int quad = lane >> 4;

  // ---- A-fragments (W rows) once into registers: 16 frags x 4 VGPR ----
  half8 af[16];
  {
    const ushort* wbase = w16 + (size_t)(rg * 64 + rt * 16 + m) * NH + kh * 512 + quad * 8;
#pragma unroll
    for (int ks = 0; ks < 16; ++ks)
      af[ks] = __builtin_bit_cast(half8, *(const uint4*)(wbase + ks * 32));
  }

  // ---- theta-phase identity: thread = (b_local = tid>>6, i_local = tid&63) ----
  const int bl = tid >> 6;         // 0..7
  const int ilc = tid & 63;        // 0..63
  const int i  = rg * 64 + ilc;    // my hidden unit
  const int b  = bg * 8 + bl;      // my batch
  float th = 0.f, s_own = 0.f, c_own = 1.f;

  // ---- init parity-0 state: far-atomic publish (LLC) ----
  {
    if ((ilc & 1) == 0)
      stx((uint*)(scT + ((size_t)(0 * 4 + bg) * 16 + bl) * 1024 + i), 0x00000000u);       // sin = 0,0
    else
      stx((uint*)(scT + ((size_t)(0 * 4 + bg) * 16 + bl + 8) * 1024 + (i - 1)), 0x3C003C00u); // cos = 1,1
  }

  unsigned step = 1;
  gbar_pub(flags, step, tid, rg, bg);
  float inpv = inp[(size_t)b * NH + i];   // t=0 prefetch drains under the wait
  gbar_wait(flags, step, tid, bg);
  ++step;

  for (int t = 0; t < T; ++t) {
    const int p = t & 1;

    // ---- B-fragments: my batch-group's 16 state rows (32 KB/block) ----
    uint4 bf[16];
    ldB(scT + ((size_t)(p * 4 + bg) * 16 + m) * 1024 + kh * 512 + quad * 8, bf);

    // ---- MFMA: two independent 8-chains, then add ----
    f32x4 D0 = {0.f, 0.f, 0.f, 0.f}, D1 = {0.f, 0.f, 0.f, 0.f};
#pragma unroll
    for (int ks = 0; ks < 8; ++ks)
      D0 = __builtin_amdgcn_mfma_f32_16x16x32_f16(af[ks], __builtin_bit_cast(half8, bf[ks]), D0, 0, 0, 0);
#pragma unroll
    for (int ks = 8; ks < 16; ++ks)
      D1 = __builtin_amdgcn_mfma_f32_16x16x32_f16(af[ks], __builtin_bit_cast(half8, bf[ks]), D1, 0, 0, 0);
    const f32x4 D = D0 + D1;

    // lane holds D rows quad*4..+3 (M) of column m (N) -> pd[kh][rt][m][quad*4..]
    *(f32x4*)&pd[(((kh * 4 + rt) * 16) + m) * 20 + quad * 4] = D;
    __syncthreads();

    // ---- theta update for (i, b) ----
    const int rti = ilc >> 4, r16 = ilc & 15;
    const float S = pd[((0 + rti) * 16 + bl) * 20 + r16] + pd[((4 + rti) * 16 + bl) * 20 + r16];
    const float C = pd[((0 + rti) * 16 + bl + 8) * 20 + r16] + pd[((4 + rti) * 16 + bl + 8) * 20 + r16];
    const float coup = s_own * C - c_own * S;   // sin*ΣWcos - cos*ΣWsin
    th = fmodf(coup + inpv + th, TWO_PI_F);
    if (th < 0.f) th += TWO_PI_F;
    float s, c;
    sincosf(th, &s, &c);
    s_own = s; c_own = c;

    if (t == T - 1) break;

    // ---- publish fp16 state via far atomics, paired lanes -> one uint each ----
    const uint hs = __builtin_bit_cast(ushort, (_Float16)s);
    const uint hc = __builtin_bit_cast(ushort, (_Float16)c);
    const uint phs = (uint)__shfl_xor((int)hs, 1, 64);
    const uint phc = (uint)__shfl_xor((int)hc, 1, 64);
    const size_t dbase = (size_t)((p ^ 1) * 4 + bg) * 16;
    if ((ilc & 1) == 0)
      stx((uint*)(scT + (dbase + bl) * 1024 + i), hs | (phs << 16));
    else
      stx((uint*)(scT + (dbase + bl + 8) * 1024 + (i - 1)), phc | (hc << 16));

    gbar_pub(flags, step, tid, rg, bg);
    inpv = inp[((size_t)(t + 1) * BATCH + b) * NH + i];   // drains under the wait
    gbar_wait(flags, step, tid, bg);
    ++step;
  }

  stF[(size_t)b * NH + i] = th;
}

// ---- readout ----
__global__ void readout(const float* __restrict__ stF,
                        const float* __restrict__ Wout,   // [10][1024]
                        const float* __restrict__ bout,   // [10]
                        float* __restrict__ out)          // [32][10]
{
  const int bb = blockIdx.x;
  const int lane = threadIdx.x;   // 64 threads
  float st[16];
#pragma unroll
  for (int u = 0; u < 16; ++u) st[u] = stF[(size_t)bb * NH + u * 64 + lane];
  for (int o = 0; o < NOUT; ++o) {
    float acc = 0.f;
#pragma unroll
    for (int u = 0; u < 16; ++u) acc += st[u] * Wout[o * NH + u * 64 + lane];
#pragma unroll
    for (int sh = 1; sh < 64; sh <<= 1) acc += __shfl_xor(acc, sh, 64);
    if (lane == 0) out[bb * NOUT + o] = acc + bout[o];
  }
}

extern "C" void kernel_launch(void* const* d_in, const int* in_sizes, int n_in,
                              void* d_out, int out_size, void* d_ws, size_t ws_size,
                              hipStream_t stream) {
  const float* x     = (const float*)d_in[0];
  const float* Wi_w  = (const float*)d_in[1];
  const float* Wi_b  = (const float*)d_in[2];
  const float* Wh    = (const float*)d_in[3];
  const float* omega = (const float*)d_in[4];
  const float* W_out = (const float*)d_in[5];
  const float* b_out = (const float*)d_in[6];

  char* ws = (char*)d_ws;
  ushort*   w16 = (ushort*)(ws + OFF_W16);
  float*    inp = (float*)(ws + OFF_INP);
  ushort*   scT = (ushort*)(ws + OFF_SCT);
  float*    stF = (float*)(ws + OFF_STF);
  unsigned* flg = (unsigned*)(ws + OFF_FLG);

  (void)hipMemsetAsync(ws + OFF_FLG, 0, 8192, stream);

  prep_w16<<<dim3(NH * NH / 256), dim3(256), 0, stream>>>(Wh, w16);
  prep_inp<<<dim3(T, BATCH), dim3(256), 0, stream>>>(x, Wi_w, Wi_b, omega, inp);

  void* args[] = { (void*)&inp, (void*)&w16, (void*)&scT, (void*)&stF, (void*)&flg };
  hipError_t err = hipLaunchCooperativeKernel((const void*)kuramoto_scan,
                                              dim3(NBLK), dim3(NTHR), args, 0, stream);
  if (err != hipSuccess) {
    // 64 blocks at <=2 blocks/CU are trivially co-resident; normal launch is safe.
    (void)hipGetLastError();
    kuramoto_scan<<<dim3(NBLK), dim3(NTHR), 0, stream>>>(inp, w16, scT, stF, flg);
  }

  readout<<<dim3(BATCH), dim3(64), 0, stream>>>(stF, W_out, b_out, (float*)d_out);
}

// Round 11
// 1052.067 us; speedup vs baseline: 1.9950x; 1.5769x over previous
//
#include <hip/hip_runtime.h>
#include <hip/hip_fp16.h>
#include <math.h>

#define TWO_PI_F 6.2831853071795864769f

constexpr int T     = 256;
constexpr int BATCH = 32;
constexpr int NIN   = 28;
constexpr int NH    = 1024;
constexpr int NOUT  = 10;

constexpr int NBLK = 64;     // 16 row-groups x 4 batch-groups
constexpr int NTHR = 512;    // 8 waves: wave w = K-slice (K=128 each)

typedef unsigned int   uint;
typedef unsigned short ushort;
typedef _Float16 half8 __attribute__((ext_vector_type(8)));
typedef float    f32x4 __attribute__((ext_vector_type(4)));

// ---- ws byte offsets ----
constexpr size_t OFF_W16 = 0;                                    // ushort [1024][1024] fp16 W = 2 MB
constexpr size_t OFF_INP = 2ull * 1024 * 1024;                   // float [T][BATCH][NH] = 32 MB
constexpr size_t OFF_SCT = OFF_INP + (size_t)T * NH * BATCH * 4; // ushort [2][4][16][1024] = 256 KB
constexpr size_t OFF_STF = OFF_SCT + 2ull * 4 * 16 * 1024 * 2;   // float [BATCH][NH] = 128 KB
constexpr size_t OFF_FLG = OFF_STF + (size_t)BATCH * NH * 4;     // step flags, 8 KB

// keep a value live without cost: forces the returning atomic whose vmcnt
// ACK = executed-at-LLC.
__device__ __forceinline__ void sink(uint v) { asm volatile("" :: "v"(v)); }

// LLC-point publish of one state word (R9-proven protocol).
__device__ __forceinline__ void stx(uint* p, uint v) {
  sink(atomicExch(p, v));
}

// B-fragment load: 4 x dwordx4 at 64B stride, one waitcnt (sc1 -> LLC).
// K-slice decomposition makes B unique per wave: 64B/thread, 32KB/block
// (was 256B/thread, 128KB/block with 4x duplication).
__device__ __forceinline__ void ldB4(const ushort* base, uint4 bf[4]) {
  asm volatile(
    "global_load_dwordx4 %0, %4, off sc1\n\t"
    "global_load_dwordx4 %1, %4, off offset:64 sc1\n\t"
    "global_load_dwordx4 %2, %4, off offset:128 sc1\n\t"
    "global_load_dwordx4 %3, %4, off offset:192 sc1\n\t"
    "s_waitcnt vmcnt(0)"
    : "=&v"(bf[0]), "=&v"(bf[1]), "=&v"(bf[2]), "=&v"(bf[3])
    : "v"(base)
    : "memory");
}

// Per-chain barrier, ATOMIC-PUBLISH protocol (R9-proven):
// data stx -> ACKed at LLC; __syncthreads drains all waves' vmcnt; flag stx.
// Consumers spin relaxed-agent (observes LLC), then read data sc1.
__device__ __forceinline__ void gbar_pub(unsigned* flags, unsigned step, int tid,
                                         int rg, int bg) {
  __syncthreads();
  if (tid == 0)
    sink(atomicExch(&flags[(bg * 16 + rg) * 32], step));
}

__device__ __forceinline__ void gbar_wait(unsigned* flags, unsigned step, int tid,
                                          int bg) {
  if (tid < 16)
    while (__hip_atomic_load(&flags[(bg * 16 + tid) * 32], __ATOMIC_RELAXED,
                             __HIP_MEMORY_SCOPE_AGENT) < step)
      ;   // no s_sleep: poll period = load latency
  __syncthreads();
}

// ---- prep: W -> fp16 ----
__global__ __launch_bounds__(256) void prep_w16(const float* __restrict__ Wh,
                                                ushort* __restrict__ w16) {
  const int m = blockIdx.x * 256 + threadIdx.x;
  w16[m] = __builtin_bit_cast(ushort, (_Float16)Wh[m]);
}

// ---- prep: inp[t][b][i] = Wi_w[i,:]·x[t,b,:] + Wi_b[i] + omega[i] ----
__global__ __launch_bounds__(256) void prep_inp(const float* __restrict__ x,
                                                const float* __restrict__ Wi_w,
                                                const float* __restrict__ Wi_b,
                                                const float* __restrict__ omega,
                                                float* __restrict__ inp) {
  const int t = blockIdx.x;
  const int b = blockIdx.y;
  const float* xr = x + ((size_t)t * BATCH + b) * NIN;
#pragma unroll
  for (int u = 0; u < 4; ++u) {
    const int i = u * 256 + threadIdx.x;
    const float* wr = Wi_w + (size_t)i * NIN;
    float acc = Wi_b[i] + omega[i];
#pragma unroll
    for (int k = 0; k < NIN; ++k) acc += xr[k] * wr[k];
    inp[((size_t)t * BATCH + b) * NH + i] = acc;
  }
}

// ---- the scan: block = (row-group, batch-group); 4 independent bg-chains.
// Wave w = K-slice (cols w*128..+127); loops over the 4 row-tiles internally.
__global__ __launch_bounds__(NTHR, 2) void kuramoto_scan(
    const float*  __restrict__ inp,   // [T][BATCH][NH]
    const ushort* __restrict__ w16,   // [1024][1024] fp16
    ushort*       __restrict__ scT,   // [2][4 bg][16 n][1024 i]; n: 0-7 sin, 8-15 cos
    float*        __restrict__ stF,   // [BATCH][NH]
    unsigned*     __restrict__ flags)
{
  // D-partials: pd[w (K-slice)][rt][n][row16 (+4 pad)] -- 8 K-partials/output
  __shared__ float pd[8 * 4 * 16 * 20];   // 40 KB

  const int tid  = threadIdx.x;
  const int bid  = blockIdx.x;
  const int rg   = bid >> 2;       // row-group: rows rg*64 .. +63
  const int bg   = bid & 3;        // batch-group: batches bg*8 .. +7
  const int lane = tid & 63;
  const int w    = tid >> 6;       // K-slice 0..7
  const int m    = lane & 15;      // A: M index / B,D: N index
  const int quad = lane >> 4;

  // ---- A-fragments: rows {rt*16+m} x K-slice w, 16 frags x 4 VGPR ----
  half8 af[16];
  {
    const ushort* wbase = w16 + (size_t)(rg * 64 + m) * NH + w * 128 + quad * 8;
#pragma unroll
    for (int rt = 0; rt < 4; ++rt)
#pragma unroll
      for (int j = 0; j < 4; ++j)
        af[rt * 4 + j] = __builtin_bit_cast(half8,
            *(const uint4*)(wbase + (size_t)rt * 16 * NH + j * 32));
  }

  // ---- theta-phase identity: thread = (b_local = tid>>6, i_local = tid&63) ----
  const int bl = tid >> 6;         // 0..7
  const int ilc = tid & 63;        // 0..63
  const int i  = rg * 64 + ilc;    // my hidden unit
  const int b  = bg * 8 + bl;      // my batch
  float th = 0.f, s_own = 0.f, c_own = 1.f;

  // ---- init parity-0 state: far-atomic publish (LLC) ----
  {
    if ((ilc & 1) == 0)
      stx((uint*)(scT + ((size_t)(0 * 4 + bg) * 16 + bl) * 1024 + i), 0x00000000u);       // sin = 0,0
    else
      stx((uint*)(scT + ((size_t)(0 * 4 + bg) * 16 + bl + 8) * 1024 + (i - 1)), 0x3C003C00u); // cos = 1,1
  }

  unsigned step = 1;
  gbar_pub(flags, step, tid, rg, bg);
  float inpv = inp[(size_t)b * NH + i];   // t=0 prefetch drains under the wait
  gbar_wait(flags, step, tid, bg);
  ++step;

  for (int t = 0; t < T; ++t) {
    const int p = t & 1;

    // ---- B-fragments: rows n=0..15 x my K-slice (64B/thread, no duplication) ----
    uint4 bf[4];
    ldB4(scT + ((size_t)(p * 4 + bg) * 16 + m) * 1024 + w * 128 + quad * 8, bf);

    // ---- MFMA: 4 independent chains of 4 (one per row-tile) ----
    f32x4 D0 = {0.f, 0.f, 0.f, 0.f}, D1 = {0.f, 0.f, 0.f, 0.f};
    f32x4 D2 = {0.f, 0.f, 0.f, 0.f}, D3 = {0.f, 0.f, 0.f, 0.f};
#pragma unroll
    for (int j = 0; j < 4; ++j) {
      const half8 bh = __builtin_bit_cast(half8, bf[j]);
      D0 = __builtin_amdgcn_mfma_f32_16x16x32_f16(af[0 * 4 + j], bh, D0, 0, 0, 0);
      D1 = __builtin_amdgcn_mfma_f32_16x16x32_f16(af[1 * 4 + j], bh, D1, 0, 0, 0);
      D2 = __builtin_amdgcn_mfma_f32_16x16x32_f16(af[2 * 4 + j], bh, D2, 0, 0, 0);
      D3 = __builtin_amdgcn_mfma_f32_16x16x32_f16(af[3 * 4 + j], bh, D3, 0, 0, 0);
    }

    // lane holds D rows quad*4..+3 (M) of column m (N) -> pd[w][rt][m][quad*4..]
    *(f32x4*)&pd[(((w * 4 + 0) * 16) + m) * 20 + quad * 4] = D0;
    *(f32x4*)&pd[(((w * 4 + 1) * 16) + m) * 20 + quad * 4] = D1;
    *(f32x4*)&pd[(((w * 4 + 2) * 16) + m) * 20 + quad * 4] = D2;
    *(f32x4*)&pd[(((w * 4 + 3) * 16) + m) * 20 + quad * 4] = D3;
    __syncthreads();

    // ---- theta update for (i, b): sum the 8 K-partials ----
    const int rti = ilc >> 4, r16 = ilc & 15;
    float S = 0.f, C = 0.f;
#pragma unroll
    for (int ww = 0; ww < 8; ++ww) {
      S += pd[((ww * 4 + rti) * 16 + bl) * 20 + r16];
      C += pd[((ww * 4 + rti) * 16 + bl + 8) * 20 + r16];
    }
    const float coup = s_own * C - c_own * S;   // sin*ΣWcos - cos*ΣWsin
    th = fmodf(coup + inpv + th, TWO_PI_F);
    if (th < 0.f) th += TWO_PI_F;
    float s, c;
    sincosf(th, &s, &c);
    s_own = s; c_own = c;

    if (t == T - 1) break;

    // ---- publish fp16 state via far atomics, paired lanes -> one uint each ----
    const uint hs = __builtin_bit_cast(ushort, (_Float16)s);
    const uint hc = __builtin_bit_cast(ushort, (_Float16)c);
    const uint phs = (uint)__shfl_xor((int)hs, 1, 64);
    const uint phc = (uint)__shfl_xor((int)hc, 1, 64);
    const size_t dbase = (size_t)((p ^ 1) * 4 + bg) * 16;
    if ((ilc & 1) == 0)
      stx((uint*)(scT + (dbase + bl) * 1024 + i), hs | (phs << 16));
    else
      stx((uint*)(scT + (dbase + bl + 8) * 1024 + (i - 1)), phc | (hc << 16));

    gbar_pub(flags, step, tid, rg, bg);
    inpv = inp[((size_t)(t + 1) * BATCH + b) * NH + i];   // drains under the wait
    gbar_wait(flags, step, tid, bg);
    ++step;
  }

  stF[(size_t)b * NH + i] = th;
}

// ---- readout ----
__global__ void readout(const float* __restrict__ stF,
                        const float* __restrict__ Wout,   // [10][1024]
                        const float* __restrict__ bout,   // [10]
                        float* __restrict__ out)          // [32][10]
{
  const int bb = blockIdx.x;
  const int lane = threadIdx.x;   // 64 threads
  float st[16];
#pragma unroll
  for (int u = 0; u < 16; ++u) st[u] = stF[(size_t)bb * NH + u * 64 + lane];
  for (int o = 0; o < NOUT; ++o) {
    float acc = 0.f;
#pragma unroll
    for (int u = 0; u < 16; ++u) acc += st[u] * Wout[o * NH + u * 64 + lane];
#pragma unroll
    for (int sh = 1; sh < 64; sh <<= 1) acc += __shfl_xor(acc, sh, 64);
    if (lane == 0) out[bb * NOUT + o] = acc + bout[o];
  }
}

extern "C" void kernel_launch(void* const* d_in, const int* in_sizes, int n_in,
                              void* d_out, int out_size, void* d_ws, size_t ws_size,
                              hipStream_t stream) {
  const float* x     = (const float*)d_in[0];
  const float* Wi_w  = (const float*)d_in[1];
  const float* Wi_b  = (const float*)d_in[2];
  const float* Wh    = (const float*)d_in[3];
  const float* omega = (const float*)d_in[4];
  const float* W_out = (const float*)d_in[5];
  const float* b_out = (const float*)d_in[6];

  char* ws = (char*)d_ws;
  ushort*   w16 = (ushort*)(ws + OFF_W16);
  float*    inp = (float*)(ws + OFF_INP);
  ushort*   scT = (ushort*)(ws + OFF_SCT);
  float*    stF = (float*)(ws + OFF_STF);
  unsigned* flg = (unsigned*)(ws + OFF_FLG);

  (void)hipMemsetAsync(ws + OFF_FLG, 0, 8192, stream);

  prep_w16<<<dim3(NH * NH / 256), dim3(256), 0, stream>>>(Wh, w16);
  prep_inp<<<dim3(T, BATCH), dim3(256), 0, stream>>>(x, Wi_w, Wi_b, omega, inp);

  void* args[] = { (void*)&inp, (void*)&w16, (void*)&scT, (void*)&stF, (void*)&flg };
  hipError_t err = hipLaunchCooperativeKernel((const void*)kuramoto_scan,
                                              dim3(NBLK), dim3(NTHR), args, 0, stream);
  if (err != hipSuccess) {
    // 64 blocks at <=2 blocks/CU are trivially co-resident; normal launch is safe.
    (void)hipGetLastError();
    kuramoto_scan<<<dim3(NBLK), dim3(NTHR), 0, stream>>>(inp, w16, scT, stF, flg);
  }

  readout<<<dim3(BATCH), dim3(64), 0, stream>>>(stF, W_out, b_out, (float*)d_out);
}

// Round 12
// 1018.564 us; speedup vs baseline: 2.0607x; 1.0329x over previous
//
#include <hip/hip_runtime.h>
#include <hip/hip_fp16.h>
#include <math.h>

#define TWO_PI_F 6.2831853071795864769f

constexpr int T     = 256;
constexpr int BATCH = 32;
constexpr int NIN   = 28;
constexpr int NH    = 1024;
constexpr int NOUT  = 10;

constexpr int NBLK = 64;     // 16 row-groups x 4 batch-groups
constexpr int NTHR = 512;    // 8 waves: wave w = K-slice (K=128 each)

typedef unsigned int   uint;
typedef unsigned short ushort;
typedef _Float16 half8 __attribute__((ext_vector_type(8)));
typedef float    f32x4 __attribute__((ext_vector_type(4)));

// ---- ws byte offsets ----
constexpr size_t OFF_W16 = 0;                                    // ushort [1024][1024] fp16 W = 2 MB
constexpr size_t OFF_INP = 2ull * 1024 * 1024;                   // float [T][BATCH][NH] = 32 MB
constexpr size_t OFF_SCT = OFF_INP + (size_t)T * NH * BATCH * 4; // ushort [2][4][16][1024] = 256 KB
constexpr size_t OFF_STF = OFF_SCT + 2ull * 4 * 16 * 1024 * 2;   // float [BATCH][NH] = 128 KB
constexpr size_t OFF_FLG = OFF_STF + (size_t)BATCH * NH * 4;     // step flags, 8 KB

// keep a value live without cost: forces the returning atomic whose vmcnt
// ACK = executed-at-LLC.
__device__ __forceinline__ void sink(uint v) { asm volatile("" :: "v"(v)); }

// LLC-point publish of one state word (R9-proven protocol).
__device__ __forceinline__ void stx(uint* p, uint v) {
  sink(atomicExch(p, v));
}

// B-fragment load: 4 x dwordx4 at 64B stride, one waitcnt (sc1 -> LLC).
__device__ __forceinline__ void ldB4(const ushort* base, uint4 bf[4]) {
  asm volatile(
    "global_load_dwordx4 %0, %4, off sc1\n\t"
    "global_load_dwordx4 %1, %4, off offset:64 sc1\n\t"
    "global_load_dwordx4 %2, %4, off offset:128 sc1\n\t"
    "global_load_dwordx4 %3, %4, off offset:192 sc1\n\t"
    "s_waitcnt vmcnt(0)"
    : "=&v"(bf[0]), "=&v"(bf[1]), "=&v"(bf[2]), "=&v"(bf[3])
    : "v"(base)
    : "memory");
}

// Per-WAVE dependency wait: wave w's K-slice (cols w*128..+127) is produced
// by exactly blocks rg' = 2w, 2w+1. Lanes 0,1 spin on those two flags; the
// wave reconverges when both observed >= step. Other waves' ldB+MFMA overlap
// with this wait -- the global max-over-16 moves to the post-compute
// __syncthreads instead of gating every ldB.
__device__ __forceinline__ void wave_wait2(unsigned* flags, unsigned step,
                                           int lane, int bg, int w) {
  if (lane < 2) {
    const unsigned* fp = &flags[(bg * 16 + 2 * w + lane) * 32];
    while (__hip_atomic_load(fp, __ATOMIC_RELAXED, __HIP_MEMORY_SCOPE_AGENT) < step)
      ;   // poll period = load latency
  }
}

// Producer flag publish (R9-proven): data stx ACKed at LLC (vmcnt drained by
// __syncthreads), then tid0 far-atomic flag.
__device__ __forceinline__ void gbar_pub(unsigned* flags, unsigned val, int tid,
                                         int rg, int bg) {
  __syncthreads();
  if (tid == 0)
    sink(atomicExch(&flags[(bg * 16 + rg) * 32], val));
}

// ---- prep: W -> fp16 ----
__global__ __launch_bounds__(256) void prep_w16(const float* __restrict__ Wh,
                                                ushort* __restrict__ w16) {
  const int m = blockIdx.x * 256 + threadIdx.x;
  w16[m] = __builtin_bit_cast(ushort, (_Float16)Wh[m]);
}

// ---- prep: inp[t][b][i] = Wi_w[i,:]·x[t,b,:] + Wi_b[i] + omega[i] ----
__global__ __launch_bounds__(256) void prep_inp(const float* __restrict__ x,
                                                const float* __restrict__ Wi_w,
                                                const float* __restrict__ Wi_b,
                                                const float* __restrict__ omega,
                                                float* __restrict__ inp) {
  const int t = blockIdx.x;
  const int b = blockIdx.y;
  const float* xr = x + ((size_t)t * BATCH + b) * NIN;
#pragma unroll
  for (int u = 0; u < 4; ++u) {
    const int i = u * 256 + threadIdx.x;
    const float* wr = Wi_w + (size_t)i * NIN;
    float acc = Wi_b[i] + omega[i];
#pragma unroll
    for (int k = 0; k < NIN; ++k) acc += xr[k] * wr[k];
    inp[((size_t)t * BATCH + b) * NH + i] = acc;
  }
}

// ---- the scan: block = (row-group, batch-group); 4 independent bg-chains.
// Wave w = K-slice; per-wave dependency wait on its 2 producer blocks.
// Lockstep safety: a block publishes state/flag only after __syncthreads
// (all 8 waves passed their waits => all 16 flags >= step), so flag s
// implies that block finished its iteration-(s-2) reads -- the parity
// buffer being overwritten at iteration t was fully read by all 16 blocks
// at iteration t-1. (Same hazard argument as the R9 global barrier.)
__global__ __launch_bounds__(NTHR, 2) void kuramoto_scan(
    const float*  __restrict__ inp,   // [T][BATCH][NH]
    const ushort* __restrict__ w16,   // [1024][1024] fp16
    ushort*       __restrict__ scT,   // [2][4 bg][16 n][1024 i]; n: 0-7 sin, 8-15 cos
    float*        __restrict__ stF,   // [BATCH][NH]
    unsigned*     __restrict__ flags)
{
  // D-partials: pd[w (K-slice)][rt][n][row16 (+4 pad)]
  __shared__ float pd[8 * 4 * 16 * 20];   // 40 KB

  const int tid  = threadIdx.x;
  const int bid  = blockIdx.x;
  const int rg   = bid >> 2;       // row-group: rows rg*64 .. +63
  const int bg   = bid & 3;        // batch-group: batches bg*8 .. +7
  const int lane = tid & 63;
  const int w    = tid >> 6;       // K-slice 0..7
  const int m    = lane & 15;      // A: M index / B,D: N index
  const int quad = lane >> 4;

  // ---- A-fragments: rows {rt*16+m} x K-slice w, 16 frags x 4 VGPR ----
  half8 af[16];
  {
    const ushort* wbase = w16 + (size_t)(rg * 64 + m) * NH + w * 128 + quad * 8;
#pragma unroll
    for (int rt = 0; rt < 4; ++rt)
#pragma unroll
      for (int j = 0; j < 4; ++j)
        af[rt * 4 + j] = __builtin_bit_cast(half8,
            *(const uint4*)(wbase + (size_t)rt * 16 * NH + j * 32));
  }

  // ---- theta-phase identity: thread = (b_local = tid>>6, i_local = tid&63) ----
  const int bl = tid >> 6;         // 0..7
  const int ilc = tid & 63;        // 0..63
  const int i  = rg * 64 + ilc;    // my hidden unit
  const int b  = bg * 8 + bl;      // my batch
  float th = 0.f, s_own = 0.f, c_own = 1.f;

  // ---- init parity-0 state: far-atomic publish (LLC) ----
  {
    if ((ilc & 1) == 0)
      stx((uint*)(scT + ((size_t)(0 * 4 + bg) * 16 + bl) * 1024 + i), 0x00000000u);       // sin = 0,0
    else
      stx((uint*)(scT + ((size_t)(0 * 4 + bg) * 16 + bl + 8) * 1024 + (i - 1)), 0x3C003C00u); // cos = 1,1
  }

  unsigned step = 1;
  gbar_pub(flags, step, tid, rg, bg);     // flag 1 guards iteration-0 reads
  float inpv = inp[(size_t)b * NH + i];   // t=0 prefetch drains under the wait

  for (int t = 0; t < T; ++t) {
    const int p = t & 1;

    // ---- per-wave wait on MY 2 producers only, then load my B-slice ----
    wave_wait2(flags, step, lane, bg, w);
    uint4 bf[4];
    ldB4(scT + ((size_t)(p * 4 + bg) * 16 + m) * 1024 + w * 128 + quad * 8, bf);

    // ---- MFMA: 4 independent chains of 4 (one per row-tile) ----
    f32x4 D0 = {0.f, 0.f, 0.f, 0.f}, D1 = {0.f, 0.f, 0.f, 0.f};
    f32x4 D2 = {0.f, 0.f, 0.f, 0.f}, D3 = {0.f, 0.f, 0.f, 0.f};
#pragma unroll
    for (int j = 0; j < 4; ++j) {
      const half8 bh = __builtin_bit_cast(half8, bf[j]);
      D0 = __builtin_amdgcn_mfma_f32_16x16x32_f16(af[0 * 4 + j], bh, D0, 0, 0, 0);
      D1 = __builtin_amdgcn_mfma_f32_16x16x32_f16(af[1 * 4 + j], bh, D1, 0, 0, 0);
      D2 = __builtin_amdgcn_mfma_f32_16x16x32_f16(af[2 * 4 + j], bh, D2, 0, 0, 0);
      D3 = __builtin_amdgcn_mfma_f32_16x16x32_f16(af[3 * 4 + j], bh, D3, 0, 0, 0);
    }

    // lane holds D rows quad*4..+3 (M) of column m (N) -> pd[w][rt][m][quad*4..]
    *(f32x4*)&pd[(((w * 4 + 0) * 16) + m) * 20 + quad * 4] = D0;
    *(f32x4*)&pd[(((w * 4 + 1) * 16) + m) * 20 + quad * 4] = D1;
    *(f32x4*)&pd[(((w * 4 + 2) * 16) + m) * 20 + quad * 4] = D2;
    *(f32x4*)&pd[(((w * 4 + 3) * 16) + m) * 20 + quad * 4] = D3;
    __syncthreads();   // all waves' pd ready AND all 16 flags >= step observed

    // ---- theta update for (i, b): sum the 8 K-partials ----
    const int rti = ilc >> 4, r16 = ilc & 15;
    float S = 0.f, C = 0.f;
#pragma unroll
    for (int ww = 0; ww < 8; ++ww) {
      S += pd[((ww * 4 + rti) * 16 + bl) * 20 + r16];
      C += pd[((ww * 4 + rti) * 16 + bl + 8) * 20 + r16];
    }
    const float coup = s_own * C - c_own * S;   // sin*ΣWcos - cos*ΣWsin
    th = fmodf(coup + inpv + th, TWO_PI_F);
    if (th < 0.f) th += TWO_PI_F;
    float s, c;
    sincosf(th, &s, &c);
    s_own = s; c_own = c;

    if (t == T - 1) break;

    // ---- publish fp16 state via far atomics, paired lanes -> one uint each ----
    const uint hs = __builtin_bit_cast(ushort, (_Float16)s);
    const uint hc = __builtin_bit_cast(ushort, (_Float16)c);
    const uint phs = (uint)__shfl_xor((int)hs, 1, 64);
    const uint phc = (uint)__shfl_xor((int)hc, 1, 64);
    const size_t dbase = (size_t)((p ^ 1) * 4 + bg) * 16;
    if ((ilc & 1) == 0)
      stx((uint*)(scT + (dbase + bl) * 1024 + i), hs | (phs << 16));
    else
      stx((uint*)(scT + (dbase + bl + 8) * 1024 + (i - 1)), phc | (hc << 16));

    gbar_pub(flags, step + 1, tid, rg, bg);               // flag guards t+1 reads
    inpv = inp[((size_t)(t + 1) * BATCH + b) * NH + i];   // drains under next wait
    ++step;
  }

  stF[(size_t)b * NH + i] = th;
}

// ---- readout ----
__global__ void readout(const float* __restrict__ stF,
                        const float* __restrict__ Wout,   // [10][1024]
                        const float* __restrict__ bout,   // [10]
                        float* __restrict__ out)          // [32][10]
{
  const int bb = blockIdx.x;
  const int lane = threadIdx.x;   // 64 threads
  float st[16];
#pragma unroll
  for (int u = 0; u < 16; ++u) st[u] = stF[(size_t)bb * NH + u * 64 + lane];
  for (int o = 0; o < NOUT; ++o) {
    float acc = 0.f;
#pragma unroll
    for (int u = 0; u < 16; ++u) acc += st[u] * Wout[o * NH + u * 64 + lane];
#pragma unroll
    for (int sh = 1; sh < 64; sh <<= 1) acc += __shfl_xor(acc, sh, 64);
    if (lane == 0) out[bb * NOUT + o] = acc + bout[o];
  }
}

extern "C" void kernel_launch(void* const* d_in, const int* in_sizes, int n_in,
                              void* d_out, int out_size, void* d_ws, size_t ws_size,
                              hipStream_t stream) {
  const float* x     = (const float*)d_in[0];
  const float* Wi_w  = (const float*)d_in[1];
  const float* Wi_b  = (const float*)d_in[2];
  const float* Wh    = (const float*)d_in[3];
  const float* omega = (const float*)d_in[4];
  const float* W_out = (const float*)d_in[5];
  const float* b_out = (const float*)d_in[6];

  char* ws = (char*)d_ws;
  ushort*   w16 = (ushort*)(ws + OFF_W16);
  float*    inp = (float*)(ws + OFF_INP);
  ushort*   scT = (ushort*)(ws + OFF_SCT);
  float*    stF = (float*)(ws + OFF_STF);
  unsigned* flg = (unsigned*)(ws + OFF_FLG);

  (void)hipMemsetAsync(ws + OFF_FLG, 0, 8192, stream);

  prep_w16<<<dim3(NH * NH / 256), dim3(256), 0, stream>>>(Wh, w16);
  prep_inp<<<dim3(T, BATCH), dim3(256), 0, stream>>>(x, Wi_w, Wi_b, omega, inp);

  void* args[] = { (void*)&inp, (void*)&w16, (void*)&scT, (void*)&stF, (void*)&flg };
  hipError_t err = hipLaunchCooperativeKernel((const void*)kuramoto_scan,
                                              dim3(NBLK), dim3(NTHR), args, 0, stream);
  if (err != hipSuccess) {
    // 64 blocks at <=2 blocks/CU are trivially co-resident; normal launch is safe.
    (void)hipGetLastError();
    kuramoto_scan<<<dim3(NBLK), dim3(NTHR), 0, stream>>>(inp, w16, scT, stF, flg);
  }

  readout<<<dim3(BATCH), dim3(64), 0, stream>>>(stF, W_out, b_out, (float*)d_out);
}